// Round 1
// baseline (335.350 us; speedup 1.0000x reference)
//
#include <hip/hip_runtime.h>
#include <math.h>

#define EPS 1.1920928955078125e-07f   // jnp.finfo(f32).eps

__device__ __forceinline__ float4 ld4(const float* __restrict__ p) { return *(const float4* __restrict__)p; }
__device__ __forceinline__ void   st4(float* __restrict__ p, float4 v) { *(float4* __restrict__)p = v; }

// ---------------------------------------------------------------------------
// Kernel 1: build WT[e][col] = W_cat[col][e], col = s*128+d (s<4: key_W[s]), 512+d: val_W
// ---------------------------------------------------------------------------
__global__ __launch_bounds__(256) void build_wt(const float* __restrict__ val_W,
                                                const float* __restrict__ key_W,
                                                float* __restrict__ WT)
{
    int idx = blockIdx.x * 256 + threadIdx.x;   // 0 .. 163839
    int col = idx % 640;
    int e   = idx / 640;
    int c = col >> 7, d = col & 127;
    float v = (c < 4) ? key_W[(size_t)((c << 7) + d) * 256 + e]
                      : val_W[(size_t)(d << 8) + e];
    WT[(size_t)e * 640 + col] = v;
}

// ---------------------------------------------------------------------------
// Kernel 2: hash + gather + GEMM(5 chunks of 128) + gates + v_gated + xn
// grid 512 (64 tokens/block), 256 threads
// ---------------------------------------------------------------------------
__global__ __launch_bounds__(256) void engram_main(
    const float* __restrict__ x,
    const int*   __restrict__ input_ids,
    const int*   __restrict__ mult,
    const float* __restrict__ embedding,
    const float* __restrict__ val_b,
    const float* __restrict__ key_b,
    const float* __restrict__ normq_w,
    const float* __restrict__ normk_w,
    const float* __restrict__ convnorm_w,
    const float* __restrict__ WT,
    float* __restrict__ out,
    float* __restrict__ XN)
{
    __shared__ int   sids[64][4];
    __shared__ float At[32][68];     // [e_local][token], pad 68 keeps 16B align, breaks conflicts
    __shared__ float Bt[32][132];    // [e_local][n_local]
    __shared__ float gates_lds[4][64];

    const int tid  = threadIdx.x;
    const int tok0 = blockIdx.x << 6;

    if (tid < 64) {
        int token = tok0 + tid;
        int b = token >> 12, t = token & 4095;
        const int* row = input_ids + (b << 12);
        unsigned g2 = (unsigned)row[t];
        unsigned g1 = (t >= 1) ? (unsigned)row[t - 1] : 0u;
        unsigned g0 = (t >= 2) ? (unsigned)row[t - 2] : 0u;
        // multipliers (2,2,3): [n][h][k] -> mult[n*6 + h*3 + k]
        sids[tid][0] = (int)(((g1 * (unsigned)mult[0]) ^ (g2 * (unsigned)mult[1])) & 4095u);
        sids[tid][1] = (int)((((g1 * (unsigned)mult[3]) ^ (g2 * (unsigned)mult[4])) & 4095u) + 4096u);
        sids[tid][2] = (int)((((g0 * (unsigned)mult[6]) ^ (g1 * (unsigned)mult[7]) ^ (g2 * (unsigned)mult[8])) & 4095u) + 8192u);
        sids[tid][3] = (int)((((g0 * (unsigned)mult[9]) ^ (g1 * (unsigned)mult[10]) ^ (g2 * (unsigned)mult[11])) & 4095u) + 12288u);
    }
    __syncthreads();

    const int ty = tid >> 4, tx = tid & 15;
    const int ty4 = ty << 2, tx8 = tx << 3;

    for (int c = 0; c < 5; ++c) {
        float acc[4][8];
        #pragma unroll
        for (int j = 0; j < 4; ++j)
            #pragma unroll
            for (int m = 0; m < 8; ++m) acc[j][m] = 0.f;

        for (int ke = 0; ke < 8; ++ke) {
            // stage A tile (gather from embedding), transposed into LDS
            #pragma unroll
            for (int it = 0; it < 2; ++it) {
                int fl = it * 256 + tid;            // 0..511
                int t  = fl >> 3, c4 = fl & 7;
                const float* src = embedding + ((size_t)sids[t][ke >> 1] << 6)
                                 + ((ke & 1) << 5) + (c4 << 2);
                float4 v = ld4(src);
                int e0 = c4 << 2;
                At[e0 + 0][t] = v.x; At[e0 + 1][t] = v.y;
                At[e0 + 2][t] = v.z; At[e0 + 3][t] = v.w;
            }
            // stage B tile from WT (already transposed -> straight copy)
            #pragma unroll
            for (int it = 0; it < 4; ++it) {
                int fl = it * 256 + tid;            // 0..1023
                int e  = fl >> 5, c4 = fl & 31;
                float4 v = ld4(WT + (size_t)(ke * 32 + e) * 640 + (c << 7) + (c4 << 2));
                st4(&Bt[e][c4 << 2], v);
            }
            __syncthreads();
            #pragma unroll
            for (int e = 0; e < 32; ++e) {
                float4 a  = ld4(&At[e][ty4]);
                float4 b0 = ld4(&Bt[e][tx8]);
                float4 b1 = ld4(&Bt[e][tx8 + 4]);
                float av[4] = {a.x, a.y, a.z, a.w};
                float bv[8] = {b0.x, b0.y, b0.z, b0.w, b1.x, b1.y, b1.z, b1.w};
                #pragma unroll
                for (int j = 0; j < 4; ++j)
                    #pragma unroll
                    for (int m = 0; m < 8; ++m)
                        acc[j][m] = fmaf(av[j], bv[m], acc[j][m]);
            }
            __syncthreads();
        }

        if (c < 4) {
            const int s = c;
            const float* kbp = key_b   + (s << 7) + tx8;
            const float* nqp = normq_w + (s << 7) + tx8;
            const float* nkp = normk_w + (s << 7) + tx8;
            float4 kba = ld4(kbp), kbb = ld4(kbp + 4);
            float4 nqa = ld4(nqp), nqb = ld4(nqp + 4);
            float4 nka = ld4(nkp), nkb = ld4(nkp + 4);
            float kb[8] = {kba.x, kba.y, kba.z, kba.w, kbb.x, kbb.y, kbb.z, kbb.w};
            float nq[8] = {nqa.x, nqa.y, nqa.z, nqa.w, nqb.x, nqb.y, nqb.z, nqb.w};
            float nk[8] = {nka.x, nka.y, nka.z, nka.w, nkb.x, nkb.y, nkb.z, nkb.w};
            #pragma unroll
            for (int j = 0; j < 4; ++j) {
                int t_loc = ty4 + j;
                int token = tok0 + t_loc;
                float kr[8]; float ks2 = 0.f;
                #pragma unroll
                for (int m = 0; m < 8; ++m) { kr[m] = acc[j][m] + kb[m]; ks2 += kr[m] * kr[m]; }
                const float* xp = x + ((((size_t)token << 2) + s) << 7) + tx8;
                float4 xa = ld4(xp), xb = ld4(xp + 4);
                float xv[8] = {xa.x, xa.y, xa.z, xa.w, xb.x, xb.y, xb.z, xb.w};
                float xs2 = 0.f, dt = 0.f;
                #pragma unroll
                for (int m = 0; m < 8; ++m) { xs2 += xv[m] * xv[m]; dt += xv[m] * nq[m] * kr[m] * nk[m]; }
                #pragma unroll
                for (int off = 1; off < 16; off <<= 1) {
                    ks2 += __shfl_xor(ks2, off);
                    xs2 += __shfl_xor(xs2, off);
                    dt  += __shfl_xor(dt,  off);
                }
                float sc = dt * rsqrtf(xs2 * (1.f / 128.f) + EPS)
                              * rsqrtf(ks2 * (1.f / 128.f) + EPS) * 0.08838834764831845f;
                float gate = 1.f / (1.f + expf(-sc));
                if (tx == 0) gates_lds[s][t_loc] = gate;
            }
        } else {
            const float* vbp = val_b + tx8;
            float4 vba = ld4(vbp), vbb = ld4(vbp + 4);
            float vb[8] = {vba.x, vba.y, vba.z, vba.w, vbb.x, vbb.y, vbb.z, vbb.w};
            float cw[4][8];
            #pragma unroll
            for (int s = 0; s < 4; ++s) {
                float4 ca = ld4(convnorm_w + (s << 7) + tx8);
                float4 cb = ld4(convnorm_w + (s << 7) + tx8 + 4);
                cw[s][0] = ca.x; cw[s][1] = ca.y; cw[s][2] = ca.z; cw[s][3] = ca.w;
                cw[s][4] = cb.x; cw[s][5] = cb.y; cw[s][6] = cb.z; cw[s][7] = cb.w;
            }
            #pragma unroll
            for (int j = 0; j < 4; ++j) {
                int t_loc = ty4 + j;
                int token = tok0 + t_loc;
                float v[8]; float s2 = 0.f;
                #pragma unroll
                for (int m = 0; m < 8; ++m) { v[m] = acc[j][m] + vb[m]; s2 += v[m] * v[m]; }
                #pragma unroll
                for (int off = 1; off < 16; off <<= 1) s2 += __shfl_xor(s2, off);
                #pragma unroll
                for (int s = 0; s < 4; ++s) {
                    float g  = gates_lds[s][t_loc];
                    float rs = rsqrtf(g * g * s2 * (1.f / 128.f) + EPS);
                    size_t base = (((size_t)token << 2) + s) << 7;
                    float4 vg0 = make_float4(v[0] * g, v[1] * g, v[2] * g, v[3] * g);
                    float4 vg1 = make_float4(v[4] * g, v[5] * g, v[6] * g, v[7] * g);
                    st4(out + base + tx8, vg0);
                    st4(out + base + tx8 + 4, vg1);
                    float f = rs * g;
                    float4 xn0 = make_float4(v[0] * f * cw[s][0], v[1] * f * cw[s][1],
                                             v[2] * f * cw[s][2], v[3] * f * cw[s][3]);
                    float4 xn1 = make_float4(v[4] * f * cw[s][4], v[5] * f * cw[s][5],
                                             v[6] * f * cw[s][6], v[7] * f * cw[s][7]);
                    st4(XN + base + tx8, xn0);
                    st4(XN + base + tx8 + 4, xn1);
                }
            }
        }
        __syncthreads();
    }
}

// ---------------------------------------------------------------------------
// Kernel 3: depthwise causal conv(K=4) + SiLU + residual add into out
// ---------------------------------------------------------------------------
__global__ __launch_bounds__(256) void conv_silu_add(const float* __restrict__ XN,
                                                     const float* __restrict__ conv_w,
                                                     float* __restrict__ out)
{
    int idx = blockIdx.x * 256 + threadIdx.x;      // < 4194304
    int d4 = idx & 31, s = (idx >> 5) & 3, token = idx >> 7;
    int t = token & 4095;
    int c0 = (s << 7) + (d4 << 2);
    float w[4][4];
    #pragma unroll
    for (int r = 0; r < 4; ++r) {
        float4 wv = ld4(conv_w + (size_t)((c0 + r) << 2));
        w[r][0] = wv.x; w[r][1] = wv.y; w[r][2] = wv.z; w[r][3] = wv.w;
    }
    float y0 = 0.f, y1 = 0.f, y2 = 0.f, y3 = 0.f;
    #pragma unroll
    for (int k = 0; k < 4; ++k) {
        int tt = t + k - 3;
        if (tt >= 0) {
            const float* p = XN + ((((size_t)(token + k - 3)) << 2) + s) * 128 + (d4 << 2);
            float4 v = ld4(p);
            y0 = fmaf(w[0][k], v.x, y0);
            y1 = fmaf(w[1][k], v.y, y1);
            y2 = fmaf(w[2][k], v.z, y2);
            y3 = fmaf(w[3][k], v.w, y3);
        }
    }
    size_t ob = ((((size_t)token) << 2) + s) * 128 + (d4 << 2);
    float4 o = ld4(out + ob);
    o.x += y0 / (1.f + expf(-y0));
    o.y += y1 / (1.f + expf(-y1));
    o.z += y2 / (1.f + expf(-y2));
    o.w += y3 / (1.f + expf(-y3));
    st4(out + ob, o);
}

// ---------------------------------------------------------------------------
extern "C" void kernel_launch(void* const* d_in, const int* in_sizes, int n_in,
                              void* d_out, int out_size, void* d_ws, size_t ws_size,
                              hipStream_t stream)
{
    const float* x          = (const float*)d_in[0];
    const int*   input_ids  = (const int*)d_in[1];
    const int*   mult       = (const int*)d_in[2];
    const float* embedding  = (const float*)d_in[3];
    const float* val_W      = (const float*)d_in[4];
    const float* val_b      = (const float*)d_in[5];
    const float* key_W      = (const float*)d_in[6];
    const float* key_b      = (const float*)d_in[7];
    const float* normq_w    = (const float*)d_in[8];
    const float* normk_w    = (const float*)d_in[9];
    const float* conv_w     = (const float*)d_in[10];
    const float* convnorm_w = (const float*)d_in[11];
    float* out = (float*)d_out;

    float* WT = (float*)d_ws;                                   // 256*640*4 = 655360 B
    float* XN = (float*)((char*)d_ws + 655360);                 // 32768*512*4 = 64 MiB

    build_wt<<<640, 256, 0, stream>>>(val_W, key_W, WT);
    engram_main<<<512, 256, 0, stream>>>(x, input_ids, mult, embedding, val_b, key_b,
                                         normq_w, normk_w, convnorm_w, WT, out, XN);
    conv_silu_add<<<16384, 256, 0, stream>>>(XN, conv_w, out);
}

// Round 2
// 286.155 us; speedup vs baseline: 1.1719x; 1.1719x over previous
//
#include <hip/hip_runtime.h>
#include <math.h>

#define EPS 1.1920928955078125e-07f   // jnp.finfo(f32).eps

__device__ __forceinline__ float4 ld4(const float* __restrict__ p) { return *(const float4* __restrict__)p; }
__device__ __forceinline__ void   st4(float* __restrict__ p, float4 v) { *(float4* __restrict__)p = v; }

// ---------------------------------------------------------------------------
// Kernel 1: WT[e][col] = W_cat[col][e]; col = s*128+d (s<4: key_W[s]), 512+d: val_W
// ---------------------------------------------------------------------------
__global__ __launch_bounds__(256) void build_wt(const float* __restrict__ val_W,
                                                const float* __restrict__ key_W,
                                                float* __restrict__ WT)
{
    int idx = blockIdx.x * 256 + threadIdx.x;   // 0 .. 163839
    int col = idx % 640;
    int e   = idx / 640;
    int c = col >> 7, d = col & 127;
    float v = (c < 4) ? key_W[(size_t)((c << 7) + d) * 256 + e]
                      : val_W[(size_t)(d << 8) + e];
    WT[(size_t)e * 640 + col] = v;
}

// ---------------------------------------------------------------------------
// Kernel 2: hash + gather + GEMM (one 128-col chunk per block)
// grid 2560 = 512 token-tiles x 5 chunks, 256 threads
// chunks 0..3 -> gates (Gbuf); chunk 4 -> v_base + S2
// ---------------------------------------------------------------------------
__global__ __launch_bounds__(256) void engram_gemm(
    const float* __restrict__ x,
    const int*   __restrict__ input_ids,
    const int*   __restrict__ mult,
    const float* __restrict__ embedding,
    const float* __restrict__ val_b,
    const float* __restrict__ key_b,
    const float* __restrict__ normq_w,
    const float* __restrict__ normk_w,
    const float* __restrict__ WT,
    float* __restrict__ v_base,
    float* __restrict__ Gbuf,
    float* __restrict__ S2buf)
{
    __shared__ int   sids[64][4];
    __shared__ float At[32][68];     // [e_local][token]
    __shared__ float Bt[32][132];    // [e_local][n_local]

    const int tid  = threadIdx.x;
    const int bid  = blockIdx.x;
    const int c    = bid % 5;
    const int tok0 = (bid / 5) << 6;

    if (tid < 64) {
        int token = tok0 + tid;
        int b = token >> 12, t = token & 4095;
        const int* row = input_ids + (b << 12);
        unsigned g2 = (unsigned)row[t];
        unsigned g1 = (t >= 1) ? (unsigned)row[t - 1] : 0u;
        unsigned g0 = (t >= 2) ? (unsigned)row[t - 2] : 0u;
        sids[tid][0] = (int)(((g1 * (unsigned)mult[0]) ^ (g2 * (unsigned)mult[1])) & 4095u);
        sids[tid][1] = (int)((((g1 * (unsigned)mult[3]) ^ (g2 * (unsigned)mult[4])) & 4095u) + 4096u);
        sids[tid][2] = (int)((((g0 * (unsigned)mult[6]) ^ (g1 * (unsigned)mult[7]) ^ (g2 * (unsigned)mult[8])) & 4095u) + 8192u);
        sids[tid][3] = (int)((((g0 * (unsigned)mult[9]) ^ (g1 * (unsigned)mult[10]) ^ (g2 * (unsigned)mult[11])) & 4095u) + 12288u);
    }
    __syncthreads();

    const int ty = tid >> 4, tx = tid & 15;
    const int ty4 = ty << 2, tx8 = tx << 3;

    float acc[4][8];
    #pragma unroll
    for (int j = 0; j < 4; ++j)
        #pragma unroll
        for (int m = 0; m < 8; ++m) acc[j][m] = 0.f;

    for (int ke = 0; ke < 8; ++ke) {
        #pragma unroll
        for (int it = 0; it < 2; ++it) {
            int fl = it * 256 + tid;            // 0..511
            int t  = fl >> 3, c4 = fl & 7;
            const float* src = embedding + ((size_t)sids[t][ke >> 1] << 6)
                             + ((ke & 1) << 5) + (c4 << 2);
            float4 v = ld4(src);
            int e0 = c4 << 2;
            At[e0 + 0][t] = v.x; At[e0 + 1][t] = v.y;
            At[e0 + 2][t] = v.z; At[e0 + 3][t] = v.w;
        }
        #pragma unroll
        for (int it = 0; it < 4; ++it) {
            int fl = it * 256 + tid;            // 0..1023
            int e  = fl >> 5, c4 = fl & 31;
            float4 v = ld4(WT + (size_t)(ke * 32 + e) * 640 + (c << 7) + (c4 << 2));
            st4(&Bt[e][c4 << 2], v);
        }
        __syncthreads();
        #pragma unroll
        for (int e = 0; e < 32; ++e) {
            float4 a  = ld4(&At[e][ty4]);
            float4 b0 = ld4(&Bt[e][tx8]);
            float4 b1 = ld4(&Bt[e][tx8 + 4]);
            float av[4] = {a.x, a.y, a.z, a.w};
            float bv[8] = {b0.x, b0.y, b0.z, b0.w, b1.x, b1.y, b1.z, b1.w};
            #pragma unroll
            for (int j = 0; j < 4; ++j)
                #pragma unroll
                for (int m = 0; m < 8; ++m)
                    acc[j][m] = fmaf(av[j], bv[m], acc[j][m]);
        }
        __syncthreads();
    }

    if (c < 4) {
        const int s = c;
        const float* kbp = key_b   + (s << 7) + tx8;
        const float* nqp = normq_w + (s << 7) + tx8;
        const float* nkp = normk_w + (s << 7) + tx8;
        float4 kba = ld4(kbp), kbb = ld4(kbp + 4);
        float4 nqa = ld4(nqp), nqb = ld4(nqp + 4);
        float4 nka = ld4(nkp), nkb = ld4(nkp + 4);
        float kb[8] = {kba.x, kba.y, kba.z, kba.w, kbb.x, kbb.y, kbb.z, kbb.w};
        float nq[8] = {nqa.x, nqa.y, nqa.z, nqa.w, nqb.x, nqb.y, nqb.z, nqb.w};
        float nk[8] = {nka.x, nka.y, nka.z, nka.w, nkb.x, nkb.y, nkb.z, nkb.w};
        #pragma unroll
        for (int j = 0; j < 4; ++j) {
            int token = tok0 + ty4 + j;
            float kr[8]; float ks2 = 0.f;
            #pragma unroll
            for (int m = 0; m < 8; ++m) { kr[m] = acc[j][m] + kb[m]; ks2 += kr[m] * kr[m]; }
            const float* xp = x + ((((size_t)token << 2) + s) << 7) + tx8;
            float4 xa = ld4(xp), xb = ld4(xp + 4);
            float xv[8] = {xa.x, xa.y, xa.z, xa.w, xb.x, xb.y, xb.z, xb.w};
            float xs2 = 0.f, dt = 0.f;
            #pragma unroll
            for (int m = 0; m < 8; ++m) { xs2 += xv[m] * xv[m]; dt += xv[m] * nq[m] * kr[m] * nk[m]; }
            #pragma unroll
            for (int off = 1; off < 16; off <<= 1) {
                ks2 += __shfl_xor(ks2, off);
                xs2 += __shfl_xor(xs2, off);
                dt  += __shfl_xor(dt,  off);
            }
            float sc = dt * rsqrtf(xs2 * (1.f / 128.f) + EPS)
                          * rsqrtf(ks2 * (1.f / 128.f) + EPS) * 0.08838834764831845f;
            float gate = 1.f / (1.f + expf(-sc));
            if (tx == 0) Gbuf[(token << 2) + s] = gate;
        }
    } else {
        const float* vbp = val_b + tx8;
        float4 vba = ld4(vbp), vbb = ld4(vbp + 4);
        float vb[8] = {vba.x, vba.y, vba.z, vba.w, vbb.x, vbb.y, vbb.z, vbb.w};
        #pragma unroll
        for (int j = 0; j < 4; ++j) {
            int token = tok0 + ty4 + j;
            float v[8]; float s2 = 0.f;
            #pragma unroll
            for (int m = 0; m < 8; ++m) { v[m] = acc[j][m] + vb[m]; s2 += v[m] * v[m]; }
            #pragma unroll
            for (int off = 1; off < 16; off <<= 1) s2 += __shfl_xor(s2, off);
            float* vp = v_base + ((size_t)token << 7) + tx8;
            st4(vp,     make_float4(v[0], v[1], v[2], v[3]));
            st4(vp + 4, make_float4(v[4], v[5], v[6], v[7]));
            if (tx == 0) S2buf[token] = s2;
        }
    }
}

// ---------------------------------------------------------------------------
// Kernel 3: fused gate/xn/conv/SiLU/residual epilogue
// thread = (token, d4), 1M threads, writes out exactly once
// ---------------------------------------------------------------------------
__global__ __launch_bounds__(256) void engram_out(
    const float* __restrict__ v_base,
    const float* __restrict__ Gbuf,
    const float* __restrict__ S2buf,
    const float* __restrict__ conv_w,
    const float* __restrict__ convnorm_w,
    float* __restrict__ out)
{
    int idx   = blockIdx.x * 256 + threadIdx.x;   // < 1048576
    int d4    = idx & 31;
    int token = idx >> 5;
    int t     = token & 4095;

    float vw[4][4];       // [k][i]
    float fwin[4][4];     // [k][s]
    float gcur[4];
    #pragma unroll
    for (int k = 0; k < 4; ++k) {
        int tt = t + k - 3;
        if (tt >= 0) {
            int tok2 = token + k - 3;
            float4 v = ld4(v_base + ((size_t)tok2 << 7) + (d4 << 2));
            vw[k][0] = v.x; vw[k][1] = v.y; vw[k][2] = v.z; vw[k][3] = v.w;
            float s2n = S2buf[tok2] * (1.f / 128.f);
            #pragma unroll
            for (int s = 0; s < 4; ++s) {
                float g = Gbuf[(tok2 << 2) + s];
                fwin[k][s] = g * rsqrtf(g * g * s2n + EPS);
                if (k == 3) gcur[s] = g;
            }
        } else {
            #pragma unroll
            for (int i = 0; i < 4; ++i) vw[k][i] = 0.f;
            #pragma unroll
            for (int s = 0; s < 4; ++s) fwin[k][s] = 0.f;
        }
    }

    #pragma unroll
    for (int s = 0; s < 4; ++s) {
        float4 cwv = ld4(convnorm_w + (s << 7) + (d4 << 2));
        float cw[4] = {cwv.x, cwv.y, cwv.z, cwv.w};
        float o[4];
        #pragma unroll
        for (int i = 0; i < 4; ++i) {
            const float* wp = conv_w + (size_t)(((s << 7) + (d4 << 2) + i) << 2);
            float4 w = ld4(wp);
            float a = w.x * vw[0][i] * fwin[0][s]
                    + w.y * vw[1][i] * fwin[1][s]
                    + w.z * vw[2][i] * fwin[2][s]
                    + w.w * vw[3][i] * fwin[3][s];
            float y = a * cw[i];
            o[i] = vw[3][i] * gcur[s] + y / (1.f + expf(-y));
        }
        st4(out + ((size_t)((token << 2) + s) << 7) + (d4 << 2),
            make_float4(o[0], o[1], o[2], o[3]));
    }
}

// ---------------------------------------------------------------------------
extern "C" void kernel_launch(void* const* d_in, const int* in_sizes, int n_in,
                              void* d_out, int out_size, void* d_ws, size_t ws_size,
                              hipStream_t stream)
{
    const float* x          = (const float*)d_in[0];
    const int*   input_ids  = (const int*)d_in[1];
    const int*   mult       = (const int*)d_in[2];
    const float* embedding  = (const float*)d_in[3];
    const float* val_W      = (const float*)d_in[4];
    const float* val_b      = (const float*)d_in[5];
    const float* key_W      = (const float*)d_in[6];
    const float* key_b      = (const float*)d_in[7];
    const float* normq_w    = (const float*)d_in[8];
    const float* normk_w    = (const float*)d_in[9];
    const float* conv_w     = (const float*)d_in[10];
    const float* convnorm_w = (const float*)d_in[11];
    float* out = (float*)d_out;

    char* ws = (char*)d_ws;
    float* WT     = (float*)ws;                       // 256*640*4   = 655360 B
    float* v_base = (float*)(ws + 655360);            // 32768*128*4 = 16 MiB
    float* Gbuf   = (float*)(ws + 655360 + 16777216); // 32768*4*4   = 512 KiB
    float* S2buf  = (float*)(ws + 655360 + 16777216 + 524288); // 128 KiB

    build_wt<<<640, 256, 0, stream>>>(val_W, key_W, WT);
    engram_gemm<<<2560, 256, 0, stream>>>(x, input_ids, mult, embedding, val_b, key_b,
                                          normq_w, normk_w, WT, v_base, Gbuf, S2buf);
    engram_out<<<4096, 256, 0, stream>>>(v_base, Gbuf, S2buf, conv_w, convnorm_w, out);
}

// Round 3
// 184.411 us; speedup vs baseline: 1.8185x; 1.5517x over previous
//
#include <hip/hip_runtime.h>
#include <math.h>

#define EPS 1.1920928955078125e-07f   // jnp.finfo(f32).eps

typedef __attribute__((ext_vector_type(8)))  short short8;
typedef __attribute__((ext_vector_type(4)))  short short4v;
typedef __attribute__((ext_vector_type(16))) float floatx16;

__device__ __forceinline__ float4 ld4(const float* __restrict__ p) { return *(const float4* __restrict__)p; }
__device__ __forceinline__ void   st4(float* __restrict__ p, float4 v) { *(float4* __restrict__)p = v; }

// f32 -> bf16 round-to-nearest-even (bit pattern in ushort)
__device__ __forceinline__ unsigned short f2bf(float f) {
    union { float f; unsigned u; } v; v.f = f;
    unsigned r = v.u + 0x7fffu + ((v.u >> 16) & 1u);
    return (unsigned short)(r >> 16);
}

// ---------------------------------------------------------------------------
// Kernel 1: pack W_cat rows into MFMA B-fragment layout, bf16.
// WbF[((nt*16 + ks)*64 + lane)*8 + j] = W_cat[n = nt*32 + (lane&31)][k = ks*16 + (lane>>5)*8 + j]
// n < 512 -> key_W[n][k]; else val_W[n-512][k].   20 n-tiles x 16 k-steps.
// ---------------------------------------------------------------------------
__global__ __launch_bounds__(256) void build_wb(const float* __restrict__ val_W,
                                                const float* __restrict__ key_W,
                                                unsigned short* __restrict__ WbF)
{
    int idx  = blockIdx.x * 256 + threadIdx.x;    // 0 .. 20479
    int lane = idx & 63;
    int ks   = (idx >> 6) & 15;
    int nt   = idx >> 10;                         // 0..19
    int n = (nt << 5) + (lane & 31);
    int k = (ks << 4) + ((lane >> 5) << 3);
    const float* src = (n < 512) ? key_W + (size_t)n * 256 + k
                                 : val_W + (size_t)(n - 512) * 256 + k;
    float4 v0 = ld4(src), v1 = ld4(src + 4);
    unsigned short o[8] = { f2bf(v0.x), f2bf(v0.y), f2bf(v0.z), f2bf(v0.w),
                            f2bf(v1.x), f2bf(v1.y), f2bf(v1.z), f2bf(v1.w) };
    unsigned short* dst = WbF + (size_t)idx * 8;
    *(short4v*)dst       = *(short4v*)&o[0];
    *(short4v*)(dst + 4) = *(short4v*)&o[4];
}

// ---------------------------------------------------------------------------
// Kernel 2: hash + gather(bf16->LDS) + MFMA GEMM + epilogue
// grid 2560 = 512 token-tiles x 5 chunks; 256 threads (4 waves)
// wave w owns n-tile (c*4+w) [32 cols] x 2 m-tiles [64 tokens], K=256 in 16 steps
// ---------------------------------------------------------------------------
__global__ __launch_bounds__(256) void engram_gemm(
    const float* __restrict__ x,
    const int*   __restrict__ input_ids,
    const int*   __restrict__ mult,
    const float* __restrict__ embedding,
    const float* __restrict__ val_b,
    const float* __restrict__ key_b,
    const float* __restrict__ normq_w,
    const float* __restrict__ normk_w,
    const unsigned short* __restrict__ WbF,
    float* __restrict__ v_base,
    float* __restrict__ Gbuf,
    float* __restrict__ S2buf)
{
    __shared__ int   sids[64][4];
    __shared__ short AD[64 * 260];   // union: bf16 A (stride 260 bf16) / f32 D (stride 130 f32)

    const int tid  = threadIdx.x;
    const int bid  = blockIdx.x;
    const int c    = bid % 5;
    const int tok0 = (bid / 5) << 6;

    if (tid < 64) {
        int token = tok0 + tid;
        int b = token >> 12, t = token & 4095;
        const int* row = input_ids + (b << 12);
        unsigned g2 = (unsigned)row[t];
        unsigned g1 = (t >= 1) ? (unsigned)row[t - 1] : 0u;
        unsigned g0 = (t >= 2) ? (unsigned)row[t - 2] : 0u;
        sids[tid][0] = (int)(((g1 * (unsigned)mult[0]) ^ (g2 * (unsigned)mult[1])) & 4095u);
        sids[tid][1] = (int)((((g1 * (unsigned)mult[3]) ^ (g2 * (unsigned)mult[4])) & 4095u) + 4096u);
        sids[tid][2] = (int)((((g0 * (unsigned)mult[6]) ^ (g1 * (unsigned)mult[7]) ^ (g2 * (unsigned)mult[8])) & 4095u) + 8192u);
        sids[tid][3] = (int)((((g0 * (unsigned)mult[9]) ^ (g1 * (unsigned)mult[10]) ^ (g2 * (unsigned)mult[11])) & 4095u) + 12288u);
    }
    __syncthreads();

    // ---- stage A: gather embedding rows, convert to bf16, LDS [token][k] stride 260
    #pragma unroll
    for (int it = 0; it < 4; ++it) {
        int f = it * 256 + tid;            // 0..1023 = (token, seg of 16 f32)
        int token = f >> 4, seg = f & 15;
        const float* src = embedding + ((size_t)sids[token][seg >> 2] << 6) + ((seg & 3) << 4);
        short* dst = AD + token * 260 + (seg << 4);
        #pragma unroll
        for (int i = 0; i < 4; ++i) {
            float4 v = ld4(src + (i << 2));
            unsigned short o[4] = { f2bf(v.x), f2bf(v.y), f2bf(v.z), f2bf(v.w) };
            *(short4v*)(dst + (i << 2)) = *(short4v*)&o[0];
        }
    }
    __syncthreads();

    // ---- K-loop: MFMA 32x32x16 bf16, B frags direct from global (L2-hot)
    const int lane = tid & 63;
    const int wv   = tid >> 6;           // wave id = local n-tile
    const int half = lane >> 5;
    const int mrow = lane & 31;

    const short* A0 = AD + mrow * 260 + (half << 3);
    const short* A1 = A0 + 32 * 260;
    const float4* Bf = (const float4*)WbF + (size_t)((c * 4 + wv) * 16) * 64 + lane;

    floatx16 acc0, acc1;
    #pragma unroll
    for (int r = 0; r < 16; ++r) { acc0[r] = 0.f; acc1[r] = 0.f; }

    #pragma unroll 4
    for (int ks = 0; ks < 16; ++ks) {
        union { float4 f; short8 s; } ub;
        ub.f = Bf[ks * 64];
        short4v a0l = *(const short4v*)(A0 + (ks << 4));
        short4v a0h = *(const short4v*)(A0 + (ks << 4) + 4);
        short4v a1l = *(const short4v*)(A1 + (ks << 4));
        short4v a1h = *(const short4v*)(A1 + (ks << 4) + 4);
        short8 a0 = { a0l[0], a0l[1], a0l[2], a0l[3], a0h[0], a0h[1], a0h[2], a0h[3] };
        short8 a1 = { a1l[0], a1l[1], a1l[2], a1l[3], a1h[0], a1h[1], a1h[2], a1h[3] };
        acc0 = __builtin_amdgcn_mfma_f32_32x32x16_bf16(a0, ub.s, acc0, 0, 0, 0);
        acc1 = __builtin_amdgcn_mfma_f32_32x32x16_bf16(a1, ub.s, acc1, 0, 0, 0);
    }
    __syncthreads();   // all A reads done; AD now reused as f32 D[64][130]

    // ---- write D to LDS: col = lane&31 (+32*wv), row = (r&3)+8*(r>>2)+4*half (+32*mt)
    float* D = (float*)AD;
    {
        int colw = (wv << 5) + mrow;
        int rb   = half << 2;
        #pragma unroll
        for (int r = 0; r < 16; ++r) {
            int row = (r & 3) + ((r >> 2) << 3) + rb;
            D[row * 130 + colw]        = acc0[r];
            D[(row + 32) * 130 + colw] = acc1[r];
        }
    }
    __syncthreads();

    // ---- epilogue (identical math to round 2, acc read from LDS)
    const int ty = tid >> 4, tx = tid & 15;
    const int ty4 = ty << 2, tx8 = tx << 3;

    if (c < 4) {
        const int s = c;
        const float* kbp = key_b   + (s << 7) + tx8;
        const float* nqp = normq_w + (s << 7) + tx8;
        const float* nkp = normk_w + (s << 7) + tx8;
        float4 kba = ld4(kbp), kbb = ld4(kbp + 4);
        float4 nqa = ld4(nqp), nqb = ld4(nqp + 4);
        float4 nka = ld4(nkp), nkb = ld4(nkp + 4);
        float kb[8] = {kba.x, kba.y, kba.z, kba.w, kbb.x, kbb.y, kbb.z, kbb.w};
        float nq[8] = {nqa.x, nqa.y, nqa.z, nqa.w, nqb.x, nqb.y, nqb.z, nqb.w};
        float nk[8] = {nka.x, nka.y, nka.z, nka.w, nkb.x, nkb.y, nkb.z, nkb.w};
        #pragma unroll
        for (int j = 0; j < 4; ++j) {
            int t_loc = ty4 + j;
            int token = tok0 + t_loc;
            const float* dp = D + t_loc * 130 + tx8;
            float kr[8]; float ks2 = 0.f;
            #pragma unroll
            for (int m = 0; m < 8; ++m) { kr[m] = dp[m] + kb[m]; ks2 += kr[m] * kr[m]; }
            const float* xp = x + ((((size_t)token << 2) + s) << 7) + tx8;
            float4 xa = ld4(xp), xb = ld4(xp + 4);
            float xv[8] = {xa.x, xa.y, xa.z, xa.w, xb.x, xb.y, xb.z, xb.w};
            float xs2 = 0.f, dt = 0.f;
            #pragma unroll
            for (int m = 0; m < 8; ++m) { xs2 += xv[m] * xv[m]; dt += xv[m] * nq[m] * kr[m] * nk[m]; }
            #pragma unroll
            for (int off = 1; off < 16; off <<= 1) {
                ks2 += __shfl_xor(ks2, off);
                xs2 += __shfl_xor(xs2, off);
                dt  += __shfl_xor(dt,  off);
            }
            float sc = dt * rsqrtf(xs2 * (1.f / 128.f) + EPS)
                          * rsqrtf(ks2 * (1.f / 128.f) + EPS) * 0.08838834764831845f;
            float gate = 1.f / (1.f + expf(-sc));
            if (tx == 0) Gbuf[(token << 2) + s] = gate;
        }
    } else {
        const float* vbp = val_b + tx8;
        float4 vba = ld4(vbp), vbb = ld4(vbp + 4);
        float vb[8] = {vba.x, vba.y, vba.z, vba.w, vbb.x, vbb.y, vbb.z, vbb.w};
        #pragma unroll
        for (int j = 0; j < 4; ++j) {
            int t_loc = ty4 + j;
            int token = tok0 + t_loc;
            const float* dp = D + t_loc * 130 + tx8;
            float v[8]; float s2 = 0.f;
            #pragma unroll
            for (int m = 0; m < 8; ++m) { v[m] = dp[m] + vb[m]; s2 += v[m] * v[m]; }
            #pragma unroll
            for (int off = 1; off < 16; off <<= 1) s2 += __shfl_xor(s2, off);
            float* vp = v_base + ((size_t)token << 7) + tx8;
            st4(vp,     make_float4(v[0], v[1], v[2], v[3]));
            st4(vp + 4, make_float4(v[4], v[5], v[6], v[7]));
            if (tx == 0) S2buf[token] = s2;
        }
    }
}

// ---------------------------------------------------------------------------
// Kernel 3: fused gate/xn/conv/SiLU/residual epilogue (unchanged from round 2)
// ---------------------------------------------------------------------------
__global__ __launch_bounds__(256) void engram_out(
    const float* __restrict__ v_base,
    const float* __restrict__ Gbuf,
    const float* __restrict__ S2buf,
    const float* __restrict__ conv_w,
    const float* __restrict__ convnorm_w,
    float* __restrict__ out)
{
    int idx   = blockIdx.x * 256 + threadIdx.x;   // < 1048576
    int d4    = idx & 31;
    int token = idx >> 5;
    int t     = token & 4095;

    float vw[4][4];
    float fwin[4][4];
    float gcur[4];
    #pragma unroll
    for (int k = 0; k < 4; ++k) {
        int tt = t + k - 3;
        if (tt >= 0) {
            int tok2 = token + k - 3;
            float4 v = ld4(v_base + ((size_t)tok2 << 7) + (d4 << 2));
            vw[k][0] = v.x; vw[k][1] = v.y; vw[k][2] = v.z; vw[k][3] = v.w;
            float s2n = S2buf[tok2] * (1.f / 128.f);
            #pragma unroll
            for (int s = 0; s < 4; ++s) {
                float g = Gbuf[(tok2 << 2) + s];
                fwin[k][s] = g * rsqrtf(g * g * s2n + EPS);
                if (k == 3) gcur[s] = g;
            }
        } else {
            #pragma unroll
            for (int i = 0; i < 4; ++i) vw[k][i] = 0.f;
            #pragma unroll
            for (int s = 0; s < 4; ++s) fwin[k][s] = 0.f;
        }
    }

    #pragma unroll
    for (int s = 0; s < 4; ++s) {
        float4 cwv = ld4(convnorm_w + (s << 7) + (d4 << 2));
        float cw[4] = {cwv.x, cwv.y, cwv.z, cwv.w};
        float o[4];
        #pragma unroll
        for (int i = 0; i < 4; ++i) {
            const float* wp = conv_w + (size_t)(((s << 7) + (d4 << 2) + i) << 2);
            float4 w = ld4(wp);
            float a = w.x * vw[0][i] * fwin[0][s]
                    + w.y * vw[1][i] * fwin[1][s]
                    + w.z * vw[2][i] * fwin[2][s]
                    + w.w * vw[3][i] * fwin[3][s];
            float y = a * cw[i];
            o[i] = vw[3][i] * gcur[s] + y / (1.f + expf(-y));
        }
        st4(out + ((size_t)((token << 2) + s) << 7) + (d4 << 2),
            make_float4(o[0], o[1], o[2], o[3]));
    }
}

// ---------------------------------------------------------------------------
extern "C" void kernel_launch(void* const* d_in, const int* in_sizes, int n_in,
                              void* d_out, int out_size, void* d_ws, size_t ws_size,
                              hipStream_t stream)
{
    const float* x          = (const float*)d_in[0];
    const int*   input_ids  = (const int*)d_in[1];
    const int*   mult       = (const int*)d_in[2];
    const float* embedding  = (const float*)d_in[3];
    const float* val_W      = (const float*)d_in[4];
    const float* val_b      = (const float*)d_in[5];
    const float* key_W      = (const float*)d_in[6];
    const float* key_b      = (const float*)d_in[7];
    const float* normq_w    = (const float*)d_in[8];
    const float* normk_w    = (const float*)d_in[9];
    const float* conv_w     = (const float*)d_in[10];
    const float* convnorm_w = (const float*)d_in[11];
    float* out = (float*)d_out;

    char* ws = (char*)d_ws;
    unsigned short* WbF = (unsigned short*)ws;                 // 20*16*64*8*2 = 327680 B
    float* v_base = (float*)(ws + 327680);                     // 16 MiB
    float* Gbuf   = (float*)(ws + 327680 + 16777216);          // 512 KiB
    float* S2buf  = (float*)(ws + 327680 + 16777216 + 524288); // 128 KiB

    build_wb<<<80, 256, 0, stream>>>(val_W, key_W, WbF);
    engram_gemm<<<2560, 256, 0, stream>>>(x, input_ids, mult, embedding, val_b, key_b,
                                          normq_w, normk_w, WbF, v_base, Gbuf, S2buf);
    engram_out<<<4096, 256, 0, stream>>>(v_base, Gbuf, S2buf, conv_w, convnorm_w, out);
}